// Round 2
// baseline (421.807 us; speedup 1.0000x reference)
//
#include <hip/hip_runtime.h>
#include <math.h>

// Problem constants (fixed by the harness/reference):
// B=2, S=8192, H=16, D=128, W=4 (window = W+1 = 5 taps)
constexpr int B = 2;
constexpr int S = 8192;
constexpr int H = 16;
constexpr int D = 128;
constexpr int W = 4;
constexpr int HD = H * D;          // 2048 floats per s step
constexpr float SCALE = 0.08838834764831845f;  // 1/sqrt(128)

// DPP butterfly add: x += lanepermute(x). CTRL: 0xB1=quad_perm(1,0,3,2)=xor1,
// 0x4E=quad_perm(2,3,0,1)=xor2, 0x141=row_half_mirror (completes 8-lane sum
// after xor1+xor2), 0x140=row_mirror (completes 16-lane sum). All VALU-pipe.
template <int CTRL>
__device__ __forceinline__ float dpp_xadd(float x) {
    int r = __builtin_amdgcn_update_dpp(0, __float_as_int(x), CTRL, 0xF, 0xF, false);
    return x + __int_as_float(r);
}

// Full reduction across a 16-lane group: 4 DPP steps, NO ds_swizzle — the DS
// round-trip (+lgkmcnt wait) that sat on every tap's critical path is gone.
__device__ __forceinline__ float group_reduce16(float p) {
    p = dpp_xadd<0xB1>(p);    // xor 1
    p = dpp_xadd<0x4E>(p);    // xor 2
    p = dpp_xadd<0x141>(p);   // xor 4 (half-mirror)
    p = dpp_xadd<0x140>(p);   // xor 8 (mirror) -> all 16 lanes hold the sum
    return p;
}

__device__ __forceinline__ float dot8(const float4& qa, const float4& qb,
                                      const float4& ka, const float4& kb) {
    return qa.x * ka.x + qa.y * ka.y + qa.z * ka.z + qa.w * ka.w +
           qb.x * kb.x + qb.y * kb.y + qb.z * kb.z + qb.w * kb.w;
}

// One 16-lane group per (b,s,h) row; lane owns d = lane*4..+3 and d+64..+67
// (each load instruction is fully contiguous across the group). Block = 16
// groups = all 16 heads at ONE s -> 16384 blocks / 65536 waves (256 per CU,
// self-balancing). Per row, ALL 20 float4 tap loads + 5 gate scalars are
// issued before any compute (load-all-then-compute): per-wave MLP ~20 vs ~3
// in rounds 0/1, which were latency-bound (VALUBusy 20-28%, HBM 28%).
// __launch_bounds__(256,4) grants the ~110 VGPRs this needs.
// blockIdx%8 = XCD s-segment (kept from earlier rounds): the 5x k/v re-read
// across neighboring s stays in one XCD's L2.
__global__ __launch_bounds__(256, 4) void gdr_kernel(
    const float* __restrict__ q, const float* __restrict__ k,
    const float* __restrict__ v, const float* __restrict__ a,
    const float* __restrict__ b, float* __restrict__ out)
{
    const int tid  = threadIdx.x;
    const int h    = tid >> 4;        // group = head
    const int lane = tid & 15;

    const int bid = blockIdx.x;
    const int xcd = bid & 7;          // S-segment / XCD (round-robin heuristic)
    const int j   = bid >> 3;         // 0..2047
    const int c   = j & 1023;         // s within segment
    const int bb  = j >> 10;          // batch
    const int s   = xcd * (S / 8) + c;

    // 32-bit element indices: max = B*S*H*D = 33.5M < 2^31.
    const int bs  = bb * S + s;
    const int row = bs * H + h;
    const int e   = row * D + lane * 4;   // first float4; second at e+64

    if (s == 0) {
        // position 0 is special-cased: out = v_0
        *(float4*)(out + e)      = *(const float4*)(v + e);
        *(float4*)(out + e + 64) = *(const float4*)(v + e + 64);
        return;
    }

    const float4 qa = *(const float4*)(q + e);
    const float4 qb = *(const float4*)(q + e + 64);
    const float  ai = a[row];

    float4 acca = make_float4(0.f, 0.f, 0.f, 0.f);
    float4 accb = make_float4(0.f, 0.f, 0.f, 0.f);

    if (s >= W) {
        // ---- fast path (all 5 taps valid): issue EVERY load first ----
        float4 ka[W + 1], kb[W + 1], va[W + 1], vb[W + 1];
        float  bg[W + 1];
#pragma unroll
        for (int d = 0; d <= W; ++d) {          // indices static after unroll
            const int ee = e - d * HD;
            ka[d] = *(const float4*)(k + ee);
            kb[d] = *(const float4*)(k + ee + 64);
            va[d] = *(const float4*)(v + ee);
            vb[d] = *(const float4*)(v + ee + 64);
            bg[d] = b[row - d * H];
        }
        // ---- then all compute: 5 independent dot+reduce chains (ILP) ----
#pragma unroll
        for (int d = 0; d <= W; ++d) {
            float p = dot8(qa, qb, ka[d], kb[d]);
            p = group_reduce16(p);
            const float g  = __builtin_amdgcn_rcpf(1.0f + __expf(-(ai * bg[d])));
            const float wg = p * SCALE * g;
            acca.x += wg * va[d].x; acca.y += wg * va[d].y;
            acca.z += wg * va[d].z; acca.w += wg * va[d].w;
            accb.x += wg * vb[d].x; accb.y += wg * vb[d].y;
            accb.z += wg * vb[d].z; accb.w += wg * vb[d].w;
        }
    } else {
        // ---- rare path: s in {1,2,3} (6 blocks total), guarded taps ----
        for (int d = 0; d <= s; ++d) {
            const int ee = e - d * HD;
            const float4 k4a = *(const float4*)(k + ee);
            const float4 k4b = *(const float4*)(k + ee + 64);
            const float4 v4a = *(const float4*)(v + ee);
            const float4 v4b = *(const float4*)(v + ee + 64);
            float p = dot8(qa, qb, k4a, k4b);
            p = group_reduce16(p);
            const float bj = b[row - d * H];
            const float g  = __builtin_amdgcn_rcpf(1.0f + __expf(-(ai * bj)));
            const float wg = p * SCALE * g;
            acca.x += wg * v4a.x; acca.y += wg * v4a.y;
            acca.z += wg * v4a.z; acca.w += wg * v4a.w;
            accb.x += wg * v4b.x; accb.y += wg * v4b.y;
            accb.z += wg * v4b.z; accb.w += wg * v4b.w;
        }
    }

    *(float4*)(out + e)      = acca;
    *(float4*)(out + e + 64) = accb;
}

extern "C" void kernel_launch(void* const* d_in, const int* in_sizes, int n_in,
                              void* d_out, int out_size, void* d_ws, size_t ws_size,
                              hipStream_t stream) {
    const float* q = (const float*)d_in[0];
    const float* k = (const float*)d_in[1];
    const float* v = (const float*)d_in[2];
    const float* a = (const float*)d_in[3];
    const float* b = (const float*)d_in[4];
    float* out = (float*)d_out;

    // one block per (b,s): 16384 blocks, each = 16 heads x 1 s
    const int blocks = B * S;
    gdr_kernel<<<blocks, 256, 0, stream>>>(q, k, v, a, b, out);
}

// Round 4
// 393.509 us; speedup vs baseline: 1.0719x; 1.0719x over previous
//
#include <hip/hip_runtime.h>
#include <math.h>
#include <stdint.h>

// Problem constants (fixed by the harness/reference):
// B=2, S=8192, H=16, D=128, W=4 (window = W+1 = 5 taps)
constexpr int B = 2;
constexpr int S = 8192;
constexpr int H = 16;
constexpr int D = 128;
constexpr int W = 4;
constexpr int HD = H * D;               // 2048 floats per s step
constexpr int TS = 64;                  // s-rows per block
constexpr int TR = TS + W;              // 68 LDS rows (4-row halo)
constexpr int SPLIT = 36;               // rows [0,36) staged in phase A
constexpr float SCALE = 0.08838834764831845f;  // 1/sqrt(128)
constexpr int LDS_BYTES = TR * D * 4 * 2;      // k + v tiles = 69,632 B

// DPP butterfly add: x += lanepermute(x). 0xB1=xor1, 0x4E=xor2,
// 0x141=row_half_mirror (xor4), 0x140=row_mirror (xor8). All VALU-pipe.
template <int CTRL>
__device__ __forceinline__ float dpp_xadd(float x) {
    int r = __builtin_amdgcn_update_dpp(0, __float_as_int(x), CTRL, 0xF, 0xF, false);
    return x + __int_as_float(r);
}
// Full reduction across a 16-lane group: 4 DPP steps, no DS ops.
__device__ __forceinline__ float group_reduce16(float p) {
    p = dpp_xadd<0xB1>(p);
    p = dpp_xadd<0x4E>(p);
    p = dpp_xadd<0x141>(p);
    p = dpp_xadd<0x140>(p);
    return p;
}
__device__ __forceinline__ float dot8(const float4& qa, const float4& qb,
                                      const float4& ka, const float4& kb) {
    return qa.x * ka.x + qa.y * ka.y + qa.z * ka.z + qa.w * ka.w +
           qb.x * kb.x + qb.y * kb.y + qb.z * kb.z + qb.w * kb.w;
}

// Async global->LDS DMA, 16B per lane. LDS dest = wave-uniform base + lane*16
// (linear); global src is per-lane. Counts in vmcnt.
typedef const __attribute__((address_space(1))) uint32_t cg_u32;
typedef __attribute__((address_space(3))) uint32_t lds_u32;
__device__ __forceinline__ void gload_lds16(const float* g, float* l) {
    __builtin_amdgcn_global_load_lds((cg_u32*)g, (lds_u32*)l, 16, 0, 0);
}

// One 16-lane group computes one output row from LDS-resident k/v taps.
__device__ __forceinline__ void compute_row(
    const float (*k_t)[D], const float (*v_t)[D], int r, int l4,
    float4 qa, float4 qb, float ai, const float* bj,
    float* outp, bool isS0)
{
    float4 acca = make_float4(0.f, 0.f, 0.f, 0.f);
    float4 accb = make_float4(0.f, 0.f, 0.f, 0.f);
    float4 v0a = acca, v0b = accb;
#pragma unroll
    for (int d = 0; d <= W; ++d) {
        const int lr = r + W - d;              // LDS row of s-d
        const float4 ka = *(const float4*)&k_t[lr][l4];
        const float4 kb = *(const float4*)&k_t[lr][l4 + 64];
        const float4 va = *(const float4*)&v_t[lr][l4];
        const float4 vb = *(const float4*)&v_t[lr][l4 + 64];
        float p = group_reduce16(dot8(qa, qb, ka, kb));
        const float g  = __builtin_amdgcn_rcpf(1.0f + __expf(-(ai * bj[d])));
        const float wg = p * SCALE * g;
        acca.x += wg * va.x; acca.y += wg * va.y;
        acca.z += wg * va.z; acca.w += wg * va.w;
        accb.x += wg * vb.x; accb.y += wg * vb.y;
        accb.z += wg * vb.z; accb.w += wg * vb.w;
        if (d == 0) { v0a = va; v0b = vb; }    // tap-0 v == v_s (for s==0 case)
    }
    if (isS0) { acca = v0a; accb = v0b; }      // reference: out[0] = v_0
    *(float4*)outp        = acca;
    *(float4*)(outp + 64) = accb;
}

// Block = (b, h, 64 consecutive s). k/v rows [s0-4, s0+64) are DMA-staged
// into LDS exactly once (68KB in flight per block ~ 30x round-2's MLP, which
// was the measured limiter: VALUBusy 11%, HBM 25%, waves convoyed on ~3
// outstanding loads). Two-phase counted-vmcnt pipeline: compute rows 0..31
// while rows [36,68) are still landing. Occupancy 2 blocks/CU (LDS-capped)
// is intentional: latency hiding moves from TLP to the DMA queue.
__global__ __launch_bounds__(256, 2) void gdr_kernel(
    const float* __restrict__ q, const float* __restrict__ k,
    const float* __restrict__ v, const float* __restrict__ a,
    const float* __restrict__ b, float* __restrict__ out)
{
    extern __shared__ __align__(16) float smem[];
    float (*k_t)[D] = (float (*)[D])smem;
    float (*v_t)[D] = (float (*)[D])(smem + TR * D);

    const int tid  = threadIdx.x;
    const int wave = tid >> 6;
    const int lane = tid & 63;
    const int grp  = tid >> 4;        // 0..15: output-row group
    const int l4   = (tid & 15) * 4;  // float offset within row

    const int bid = blockIdx.x;
    const int xcd = bid & 7;          // S split into 8 contiguous XCD segments
    int t = bid >> 3;
    const int c  = t & 15;  t >>= 4;  // chunk within segment (16 x 64 = 1024)
    const int h  = t & 15;
    const int bb = t >> 4;
    const int s0 = xcd * (S / 8) + c * TS;

    const int sA = s0 + grp;          // this group's 4 output rows
    const int sB = sA + 16;
    const int sC = sA + 32;
    const int sD = sA + 48;

    const int rowH = bb * S * H + h;             // a/b index = rowH + s*H
    const int eA = (rowH + sA * H) * D + l4;     // q/k/v/out elem index
    const int eB = eA + 16 * HD;
    const int eC = eA + 32 * HD;
    const int eD = eA + 48 * HD;

    // ---- phase-1 prefetch (rows sA,sB): flies during the DMA wait ----
    const float4 qaA = *(const float4*)(q + eA), qbA = *(const float4*)(q + eA + 64);
    const float4 qaB = *(const float4*)(q + eB), qbB = *(const float4*)(q + eB + 64);
    const float  aiA = a[rowH + sA * H], aiB = a[rowH + sB * H];
    float bjA[W + 1], bjB[W + 1];
#pragma unroll
    for (int d = 0; d <= W; ++d) {
        const int jA = (sA - d) < 0 ? 0 : (sA - d);  // clamp: only s0==0 tile;
        bjA[d] = b[rowH + jA * H];                   // its k/v are 0 so tap = 0
        bjB[d] = b[rowH + (sB - d) * H];             // sB-d >= 12, always valid
    }

    // zero-fill the 4 history rows for the very first tile (s0==0)
    if (s0 == 0 && tid < 128) {
        const float4 z = make_float4(0.f, 0.f, 0.f, 0.f);
        ((float4*)k_t)[tid] = z;    // rows 0..3 of k_t (4 x 512B = 128 float4)
        ((float4*)v_t)[tid] = z;
    }
    __builtin_amdgcn_sched_barrier(0);   // pin: prefetch above, DMA below

    // ---- DMA stage k/v rows [s0-4, s0+64) -> LDS rows [0,68) ----
    // Each instr: 64 lanes x 16B = 2 rows (1KB). lane>>5 picks the row of the
    // pair, (lane&31)*16B the chunk; LDS dest is linear (row-major [68][128]).
    const int g0 = (rowH + (s0 - 4 + (lane >> 5)) * H) * D + (lane & 31) * 4;
    const int pSkip = (s0 == 0) ? 2 : 0;      // pairs 0,1 = zeroed history
#pragma unroll
    for (int p0 = 0; p0 < 5; ++p0) {          // phase A: pairs 0..17 (rows 0..35)
        const int p = wave + 4 * p0;
        if (p < 18 && p >= pSkip) {
            gload_lds16(k + g0 + 2 * p * HD, &k_t[2 * p][0]);
            gload_lds16(v + g0 + 2 * p * HD, &v_t[2 * p][0]);
        }
    }
    __builtin_amdgcn_sched_barrier(0);
#pragma unroll
    for (int p0 = 0; p0 < 4; ++p0) {          // phase B: rows [36,68), 8/wave
        const int r0 = SPLIT + 2 * (wave + 4 * p0);
        gload_lds16(k + g0 + r0 * HD, &k_t[r0][0]);
        gload_lds16(v + g0 + r0 * HD, &v_t[r0][0]);
    }
    __builtin_amdgcn_sched_barrier(0);

    // wait own phase-A DMA (+prefetch, +zero-fill); leave B's 8 loads flying
    asm volatile("s_waitcnt vmcnt(8) lgkmcnt(0)" ::: "memory");
    __builtin_amdgcn_s_barrier();
    __builtin_amdgcn_sched_barrier(0);        // rule #18: no hoist past barrier

    // ---- phase-2 prefetch: issued now, lands under phase-1 compute ----
    const float4 qaC = *(const float4*)(q + eC), qbC = *(const float4*)(q + eC + 64);
    const float4 qaD = *(const float4*)(q + eD), qbD = *(const float4*)(q + eD + 64);
    const float  aiC = a[rowH + sC * H], aiD = a[rowH + sD * H];
    float bjC[W + 1], bjD[W + 1];
#pragma unroll
    for (int d = 0; d <= W; ++d) {
        bjC[d] = b[rowH + (sC - d) * H];
        bjD[d] = b[rowH + (sD - d) * H];
    }

    // ---- phase-1 compute: rows grp, grp+16 (LDS rows <= 35, all staged) ----
    compute_row(k_t, v_t, grp,      l4, qaA, qbA, aiA, bjA, out + eA, sA == 0);
    compute_row(k_t, v_t, grp + 16, l4, qaB, qbB, aiB, bjB, out + eB, false);

    asm volatile("s_waitcnt vmcnt(0)" ::: "memory");   // phase-B DMA done
    __builtin_amdgcn_s_barrier();
    __builtin_amdgcn_sched_barrier(0);

    // ---- phase-2 compute: rows grp+32, grp+48 ----
    compute_row(k_t, v_t, grp + 32, l4, qaC, qbC, aiC, bjC, out + eC, false);
    compute_row(k_t, v_t, grp + 48, l4, qaD, qbD, aiD, bjD, out + eD, false);
}

extern "C" void kernel_launch(void* const* d_in, const int* in_sizes, int n_in,
                              void* d_out, int out_size, void* d_ws, size_t ws_size,
                              hipStream_t stream) {
    const float* q = (const float*)d_in[0];
    const float* k = (const float*)d_in[1];
    const float* v = (const float*)d_in[2];
    const float* a = (const float*)d_in[3];
    const float* b = (const float*)d_in[4];
    float* out = (float*)d_out;

    // B(2) x H(16) x s-chunks(128) = 4096 blocks, 68KB dynamic LDS each
    const int blocks = B * H * (S / TS);
    gdr_kernel<<<blocks, 256, LDS_BYTES, stream>>>(q, k, v, a, b, out);
}